// Round 1
// 261.266 us; speedup vs baseline: 1.4432x; 1.4432x over previous
//
#include <hip/hip_runtime.h>
#include <hip/hip_bf16.h>
#include <math.h>

#define Bn 16
#define Cc 256
#define Oo 128
#define HWn 4096
#define Ntot 65536   // Bn*HWn
#define BK 64
#define NBLK 512     // conv blocks per z (32 x 16)

typedef __attribute__((ext_vector_type(8))) __bf16 bf16x8;
typedef __attribute__((ext_vector_type(4))) float f32x4;

__device__ __forceinline__ unsigned short f2bf(float f) {
    unsigned u = __builtin_bit_cast(unsigned, f);
    u = (u + 0x7FFFu + ((u >> 16) & 1u)) >> 16;
    return (unsigned short)u;
}

// ---------------- fused conv1x1 (bf16 MFMA) + bias + per-channel partial stats ----------------
// z=0: tg = wg_w @ g + wg_b ; z=1: tx = wx_w @ x + wx_b
// Tile: M=128 (o) x N=128 (hw), K=256, BK=64. 4 waves in 2x2, each wave 64x64 (4x4 frags).
// Register-prefetch pipeline: loads for tile k+1 issued right after the LDS-ready barrier,
// in flight during the MFMA phase of tile k. Stats go to per-block partials (no atomics).
__global__ __launch_bounds__(256, 2)
void conv_mfma(const float* __restrict__ gin, const float* __restrict__ xin,
               const float* __restrict__ wgw, const float* __restrict__ wgb,
               const float* __restrict__ wxw, const float* __restrict__ wxb,
               float* __restrict__ tg, float* __restrict__ tx,
               float* __restrict__ pstat)
{
    const int z = blockIdx.z;
    const float* in   = z ? xin : gin;
    const float* w    = z ? wxw : wgw;
    const float* bias = z ? wxb : wgb;
    float* out  = z ? tx : tg;

    __shared__ short A_s[128][72];        // [o][c] bf16, row stride 144 B
    __shared__ unsigned int B_s[32][129]; // [c2][hw] packed (bf16 c, bf16 c+1), row 516 B

    const int t    = threadIdx.x;
    const int b    = blockIdx.y;
    const int hw0  = blockIdx.x * 128;
    const int lane = t & 63;
    const int wv   = t >> 6;
    const int m0   = (wv & 1) * 64;   // o offset in tile
    const int n0   = (wv >> 1) * 64;  // hw offset in tile
    const int q    = lane >> 4;
    const int r    = lane & 15;

    // staging indices
    const int su  = t & 31;   // B: hw block (hw = su*4)
    const int sc2 = t >> 5;   // B: c-pair row 0..7
    const int au  = t & 15;   // A: c block (c = au*4)
    const int ao  = t >> 4;   // A: o 0..15 (step 16)

    f32x4 acc[4][4];
#pragma unroll
    for (int i = 0; i < 4; i++)
#pragma unroll
        for (int j = 0; j < 4; j++) acc[i][j] = (f32x4){0.f, 0.f, 0.f, 0.f};

    // in-flight staging registers (one K-tile): B first (big stream), then A (L2-hot weights)
    float4 bv[8];
    float4 av[8];
    auto issue = [&](int kc) {
#pragma unroll
        for (int i = 0; i < 4; i++) {
            const int c = kc + (sc2 + i * 8) * 2;
            bv[2 * i + 0] = *(const float4*)(in + (b * Cc + c) * HWn + hw0 + su * 4);
            bv[2 * i + 1] = *(const float4*)(in + (b * Cc + c + 1) * HWn + hw0 + su * 4);
        }
#pragma unroll
        for (int i = 0; i < 8; i++)
            av[i] = *(const float4*)(w + (ao + i * 16) * Cc + kc + au * 4);
    };

    issue(0);

    for (int kc = 0; kc < Cc; kc += BK) {
        // convert staged regs -> LDS (compiler inserts the vmcnt waits)
#pragma unroll
        for (int i = 0; i < 4; i++) {
            const int c2 = sc2 + i * 8;
            const float4 v0 = bv[2 * i + 0];
            const float4 v1 = bv[2 * i + 1];
            uint4 pk;
            pk.x = (unsigned)f2bf(v0.x) | ((unsigned)f2bf(v1.x) << 16);
            pk.y = (unsigned)f2bf(v0.y) | ((unsigned)f2bf(v1.y) << 16);
            pk.z = (unsigned)f2bf(v0.z) | ((unsigned)f2bf(v1.z) << 16);
            pk.w = (unsigned)f2bf(v0.w) | ((unsigned)f2bf(v1.w) << 16);
            *(uint4*)&B_s[c2][su * 4] = pk;   // contiguous b128 write: conflict-free
        }
#pragma unroll
        for (int i = 0; i < 8; i++) {
            const int o = ao + i * 16;
            const float4 v = av[i];
            unsigned int lo = (unsigned)f2bf(v.x) | ((unsigned)f2bf(v.y) << 16);
            unsigned int hi = (unsigned)f2bf(v.z) | ((unsigned)f2bf(v.w) << 16);
            *(uint2*)&A_s[o][au * 4] = make_uint2(lo, hi);
        }
        __syncthreads();   // LDS ready

        // prefetch next K-tile while this tile's MFMA runs
        if (kc + BK < Cc) issue(kc + BK);

#pragma unroll
        for (int ks = 0; ks < 2; ks++) {
            bf16x8 af[4];
#pragma unroll
            for (int mi = 0; mi < 4; mi++)
                af[mi] = *(const bf16x8*)&A_s[m0 + mi * 16 + r][ks * 32 + q * 8];
#pragma unroll
            for (int ni = 0; ni < 4; ni++) {
                unsigned int bw[4];
                const int nn = n0 + ni * 16 + r;
                const int row = ks * 16 + q * 4;
#pragma unroll
                for (int jj = 0; jj < 4; jj++) bw[jj] = B_s[row + jj][nn];
                const bf16x8 bfr = *(const bf16x8*)bw;
#pragma unroll
                for (int mi = 0; mi < 4; mi++)
                    acc[mi][ni] = __builtin_amdgcn_mfma_f32_16x16x32_bf16(af[mi], bfr, acc[mi][ni], 0, 0, 0);
            }
        }
        __syncthreads();   // LDS consumed
    }

    // epilogue: bias, store fp32, per-o stats -> LDS combine -> per-block partial store
    float* red = (float*)&A_s[0][0];   // 4*128 floats, reuse of A_s (all MFMA reads done)
    const int hf = wv >> 1;            // which n-half this wave covers
#pragma unroll
    for (int mi = 0; mi < 4; mi++) {
#pragma unroll
        for (int reg = 0; reg < 4; reg++) {
            const int o = m0 + mi * 16 + q * 4 + reg;
            const float bo = bias[o];
            float s1 = 0.f, s2 = 0.f;
#pragma unroll
            for (int ni = 0; ni < 4; ni++) {
                const float v = acc[mi][ni][reg] + bo;
                out[((b * Oo + o) << 12) + hw0 + n0 + ni * 16 + r] = v;
                s1 += v; s2 += v * v;
            }
#pragma unroll
            for (int d = 1; d < 16; d <<= 1) {
                s1 += __shfl_xor(s1, d);
                s2 += __shfl_xor(s2, d);
            }
            if (r == 0) {
                red[(hf * 2 + 0) * 128 + o] = s1;
                red[(hf * 2 + 1) * 128 + o] = s2;
            }
        }
    }
    __syncthreads();
    {
        const int o = t & 127;
        const int s = t >> 7;
        const float v = red[(0 + s) * 128 + o] + red[(2 + s) * 128 + o];
        const int blk = blockIdx.y * 32 + blockIdx.x;
        pstat[(size_t)(((((z << 7) | o) << 1) | s) << 9) | blk] = v;
    }
}

// ---------------- reduce partial stats, build per-channel coefficients ----------------
// 1 block x 256 threads: t<128 -> z=0 (g conv), t>=128 -> z=1 (x conv)
__global__ void finalize1(const float* __restrict__ pstat,
                          const float* __restrict__ wg_gamma, const float* __restrict__ wg_beta,
                          const float* __restrict__ wx_gamma, const float* __restrict__ wx_beta,
                          const float* __restrict__ psi_w, float4* __restrict__ coef)
{
    const int t = threadIdx.x;
    const int z = t >> 7;
    const int o = t & 127;
    const float4* p1 = (const float4*)(pstat + (size_t)(((((z << 7) | o) << 1) | 0) << 9));
    const float4* p2 = (const float4*)(pstat + (size_t)(((((z << 7) | o) << 1) | 1) << 9));
    float s1 = 0.f, s2 = 0.f;
#pragma unroll 4
    for (int i = 0; i < 128; i++) {
        const float4 a = p1[i];
        const float4 c = p2[i];
        s1 += (a.x + a.y) + (a.z + a.w);
        s2 += (c.x + c.y) + (c.z + c.w);
    }
    const float invN = 1.f / (float)Ntot;
    const float m = s1 * invN;
    const float v = s2 * invN - m * m;
    const float sc = (z ? wx_gamma : wg_gamma)[o] * rsqrtf(v + 1e-5f);
    const float sh = (z ? wx_beta : wg_beta)[o] - m * sc;
    __shared__ float shsc[2][128], shsh[2][128];
    shsc[z][o] = sc; shsh[z][o] = sh;
    __syncthreads();
    if (t < 128)
        coef[t] = make_float4(shsc[0][t], shsc[1][t], shsh[0][t] + shsh[1][t], psi_w[t]);
}

// ---------------- psi: S[p] = psi_b + sum_o pw*relu(gs*tg + xs*tx + c), + stats partials ----
// 1024 blocks x 256 threads. Each wave: 64 pixels x 32 channels; LDS combine across 4 waves.
__global__ __launch_bounds__(256)
void psi_partial(const float* __restrict__ tg, const float* __restrict__ tx,
                 const float4* __restrict__ coef, const float* __restrict__ psi_b,
                 float* __restrict__ S, float* __restrict__ pp)
{
    const int lane = threadIdx.x & 63;
    const int wv   = threadIdx.x >> 6;
    const int p    = blockIdx.x * 64 + lane;
    const int b    = p >> 12;
    const int hw   = p & 4095;
    const float* g0 = tg + (((size_t)(b * Oo + wv * 32)) << 12) + hw;
    const float* x0 = tx + (((size_t)(b * Oo + wv * 32)) << 12) + hw;
    float s = 0.f;
#pragma unroll
    for (int oi = 0; oi < 32; oi++) {
        const float4 cf = coef[wv * 32 + oi];
        const float gv = g0[(size_t)oi << 12];
        const float xv = x0[(size_t)oi << 12];
        s += cf.w * fmaxf(cf.x * gv + cf.y * xv + cf.z, 0.f);
    }
    __shared__ float sr[4][64];
    sr[wv][lane] = s;
    __syncthreads();
    if (wv == 0) {
        float st = s + sr[1][lane] + sr[2][lane] + sr[3][lane] + psi_b[0];
        S[p] = st;
        float s1 = st, s2 = st * st;
#pragma unroll
        for (int d = 1; d < 64; d <<= 1) {
            s1 += __shfl_xor(s1, d);
            s2 += __shfl_xor(s2, d);
        }
        if (lane == 0) {
            pp[blockIdx.x]        = s1;
            pp[1024 + blockIdx.x] = s2;
        }
    }
}

// ---------------- reduce psi stats partials -> scale/shift ----------------
__global__ void finalize2(const float* __restrict__ pp, const float* __restrict__ psi_gamma,
                          const float* __restrict__ psi_beta, float* __restrict__ pc)
{
    const int t = threadIdx.x;
    float s1 = pp[t] + pp[256 + t] + pp[512 + t] + pp[768 + t];
    float s2 = pp[1024 + t] + pp[1280 + t] + pp[1536 + t] + pp[1792 + t];
#pragma unroll
    for (int d = 1; d < 64; d <<= 1) {
        s1 += __shfl_xor(s1, d);
        s2 += __shfl_xor(s2, d);
    }
    __shared__ float a1[4], a2[4];
    const int wid = t >> 6, lid = t & 63;
    if (lid == 0) { a1[wid] = s1; a2[wid] = s2; }
    __syncthreads();
    if (t == 0) {
        const float invN = 1.f / (float)Ntot;
        const float ts1 = a1[0] + a1[1] + a1[2] + a1[3];
        const float ts2 = a2[0] + a2[1] + a2[2] + a2[3];
        const float m = ts1 * invN;
        const float v = ts2 * invN - m * m;
        const float ps = psi_gamma[0] * rsqrtf(v + 1e-5f);
        pc[0] = ps;
        pc[1] = psi_beta[0] - m * ps;
    }
}

// ---------------- out = x * sigmoid(pscale*s + pshift) ----------------
__global__ __launch_bounds__(256)
void final_mul_kernel(const float* __restrict__ x, const float* __restrict__ S,
                      const float* __restrict__ pc, float* __restrict__ out)
{
    const size_t i = ((size_t)blockIdx.x * 256 + threadIdx.x) * 4;
    const int hw = (int)(i & 4095);
    const size_t bc = i >> 12;
    const int b = (int)(bc >> 8);
    const float ps = pc[0], psh = pc[1];
    const float4 xv = *(const float4*)(x + i);
    const float4 sv = *(const float4*)(S + ((size_t)b << 12) + hw);
    float4 r;
    r.x = xv.x * (1.f / (1.f + __expf(-(ps * sv.x + psh))));
    r.y = xv.y * (1.f / (1.f + __expf(-(ps * sv.y + psh))));
    r.z = xv.z * (1.f / (1.f + __expf(-(ps * sv.z + psh))));
    r.w = xv.w * (1.f / (1.f + __expf(-(ps * sv.w + psh))));
    *(float4*)(out + i) = r;
}

extern "C" void kernel_launch(void* const* d_in, const int* in_sizes, int n_in,
                              void* d_out, int out_size, void* d_ws, size_t ws_size,
                              hipStream_t stream)
{
    const float* g         = (const float*)d_in[0];
    const float* x         = (const float*)d_in[1];
    const float* wg_w      = (const float*)d_in[2];
    const float* wg_b      = (const float*)d_in[3];
    const float* wg_gamma  = (const float*)d_in[4];
    const float* wg_beta   = (const float*)d_in[5];
    const float* wx_w      = (const float*)d_in[6];
    const float* wx_b      = (const float*)d_in[7];
    const float* wx_gamma  = (const float*)d_in[8];
    const float* wx_beta   = (const float*)d_in[9];
    const float* psi_w     = (const float*)d_in[10];
    const float* psi_b     = (const float*)d_in[11];
    const float* psi_gamma = (const float*)d_in[12];
    const float* psi_beta  = (const float*)d_in[13];

    float* out = (float*)d_out;
    // d_out doubles as scratch for the two conv outputs (exactly 64 MB),
    // fully overwritten by final_mul_kernel afterwards.
    float* tg = out;
    float* tx = out + (size_t)Bn * Oo * HWn;   // +8388608

    float* ws    = (float*)d_ws;
    float* S     = ws;                          // 65536 floats (written once, no memset)
    float* pstat = ws + 65536;                  // 262144 floats: [z][o][s1|s2][512 blocks]
    float* pp    = ws + 65536 + 262144;         // 2048 floats: psi stats partials
    float4* coef = (float4*)(ws + 329728);      // 128 float4 (16B aligned)
    float* pc    = ws + 330240;                 // 2

    // no memsets: every buffer is fully written before being read

    conv_mfma<<<dim3(HWn / 128, Bn, 2), 256, 0, stream>>>(
        g, x, wg_w, wg_b, wx_w, wx_b, tg, tx, pstat);
    finalize1<<<1, 256, 0, stream>>>(pstat, wg_gamma, wg_beta, wx_gamma, wx_beta,
                                     psi_w, coef);
    psi_partial<<<Ntot / 64, 256, 0, stream>>>(tg, tx, coef, psi_b, S, pp);
    finalize2<<<1, 256, 0, stream>>>(pp, psi_gamma, psi_beta, pc);
    final_mul_kernel<<<(Ntot * Cc) / (4 * 256), 256, 0, stream>>>(x, S, pc, out);
}

// Round 3
// 257.248 us; speedup vs baseline: 1.4658x; 1.0156x over previous
//
#include <hip/hip_runtime.h>
#include <hip/hip_bf16.h>
#include <math.h>

#define Bn 16
#define Cc 256
#define Oo 128
#define HWn 4096
#define Ntot 65536   // Bn*HWn
#define BK 64

typedef __attribute__((ext_vector_type(8))) __bf16 bf16x8;
typedef __attribute__((ext_vector_type(4))) float f32x4;

__device__ __forceinline__ unsigned short f2bf(float f) {
    unsigned u = __builtin_bit_cast(unsigned, f);
    u = (u + 0x7FFFu + ((u >> 16) & 1u)) >> 16;
    return (unsigned short)u;
}

__device__ __forceinline__ float bf2f(unsigned short h) {
    return __builtin_bit_cast(float, (unsigned)h << 16);
}

// ---------------- fused conv1x1 (bf16 MFMA) + per-channel partial stats ----------------
// z=0: tg = wg_w @ g ; z=1: tx = wx_w @ x   (biases cancel exactly under BN and are dropped)
// Output stored as bf16 [b][o][hw]. Stats computed from exact fp32 accumulators.
// Tile: M=128 (o) x N=128 (hw), K=256, BK=64. 4 waves in 2x2, each wave 64x64 (4x4 frags).
// Register-prefetch pipeline: loads for tile k+1 issued right after the LDS-ready barrier.
__global__ __launch_bounds__(256, 2)
void conv_mfma(const float* __restrict__ gin, const float* __restrict__ xin,
               const float* __restrict__ wgw, const float* __restrict__ wxw,
               unsigned short* __restrict__ tg, unsigned short* __restrict__ tx,
               float* __restrict__ pstat)
{
    const int z = blockIdx.z;
    const float* in = z ? xin : gin;
    const float* w  = z ? wxw : wgw;
    unsigned short* out = z ? tx : tg;

    __shared__ short A_s[128][72];        // [o][c] bf16, row stride 144 B
    __shared__ unsigned int B_s[32][129]; // [c2][hw] packed (bf16 c, bf16 c+1), row 516 B

    const int t    = threadIdx.x;
    const int b    = blockIdx.y;
    const int hw0  = blockIdx.x * 128;
    const int lane = t & 63;
    const int wv   = t >> 6;
    const int m0   = (wv & 1) * 64;   // o offset in tile
    const int n0   = (wv >> 1) * 64;  // hw offset in tile
    const int q    = lane >> 4;
    const int r    = lane & 15;

    // staging indices
    const int su  = t & 31;   // B: hw block (hw = su*4)
    const int sc2 = t >> 5;   // B: c-pair row 0..7
    const int au  = t & 15;   // A: c block (c = au*4)
    const int ao  = t >> 4;   // A: o 0..15 (step 16)

    f32x4 acc[4][4];
#pragma unroll
    for (int i = 0; i < 4; i++)
#pragma unroll
        for (int j = 0; j < 4; j++) acc[i][j] = (f32x4){0.f, 0.f, 0.f, 0.f};

    // in-flight staging registers (one K-tile)
    float4 bv[8];
    float4 av[8];
    auto issue = [&](int kc) {
#pragma unroll
        for (int i = 0; i < 4; i++) {
            const int c = kc + (sc2 + i * 8) * 2;
            bv[2 * i + 0] = *(const float4*)(in + (b * Cc + c) * HWn + hw0 + su * 4);
            bv[2 * i + 1] = *(const float4*)(in + (b * Cc + c + 1) * HWn + hw0 + su * 4);
        }
#pragma unroll
        for (int i = 0; i < 8; i++)
            av[i] = *(const float4*)(w + (ao + i * 16) * Cc + kc + au * 4);
    };

    issue(0);

    for (int kc = 0; kc < Cc; kc += BK) {
        // convert staged regs -> LDS (compiler inserts the vmcnt waits)
#pragma unroll
        for (int i = 0; i < 4; i++) {
            const int c2 = sc2 + i * 8;
            const float4 v0 = bv[2 * i + 0];
            const float4 v1 = bv[2 * i + 1];
            uint4 pk;
            pk.x = (unsigned)f2bf(v0.x) | ((unsigned)f2bf(v1.x) << 16);
            pk.y = (unsigned)f2bf(v0.y) | ((unsigned)f2bf(v1.y) << 16);
            pk.z = (unsigned)f2bf(v0.z) | ((unsigned)f2bf(v1.z) << 16);
            pk.w = (unsigned)f2bf(v0.w) | ((unsigned)f2bf(v1.w) << 16);
            *(uint4*)&B_s[c2][su * 4] = pk;   // contiguous b128 write: conflict-free
        }
#pragma unroll
        for (int i = 0; i < 8; i++) {
            const int o = ao + i * 16;
            const float4 v = av[i];
            unsigned int lo = (unsigned)f2bf(v.x) | ((unsigned)f2bf(v.y) << 16);
            unsigned int hi = (unsigned)f2bf(v.z) | ((unsigned)f2bf(v.w) << 16);
            *(uint2*)&A_s[o][au * 4] = make_uint2(lo, hi);
        }
        __syncthreads();   // LDS ready

        // prefetch next K-tile while this tile's MFMA runs
        if (kc + BK < Cc) issue(kc + BK);

#pragma unroll
        for (int ks = 0; ks < 2; ks++) {
            bf16x8 af[4];
#pragma unroll
            for (int mi = 0; mi < 4; mi++)
                af[mi] = *(const bf16x8*)&A_s[m0 + mi * 16 + r][ks * 32 + q * 8];
#pragma unroll
            for (int ni = 0; ni < 4; ni++) {
                unsigned int bw[4];
                const int nn = n0 + ni * 16 + r;
                const int row = ks * 16 + q * 4;
#pragma unroll
                for (int jj = 0; jj < 4; jj++) bw[jj] = B_s[row + jj][nn];
                const bf16x8 bfr = *(const bf16x8*)bw;
#pragma unroll
                for (int mi = 0; mi < 4; mi++)
                    acc[mi][ni] = __builtin_amdgcn_mfma_f32_16x16x32_bf16(af[mi], bfr, acc[mi][ni], 0, 0, 0);
            }
        }
        __syncthreads();   // LDS consumed
    }

    // epilogue: store bf16, per-o stats -> LDS combine -> per-block partial store
    float* red = (float*)&A_s[0][0];   // 4*128 floats, reuse of A_s (all MFMA reads done)
    const int hf = wv >> 1;            // which n-half this wave covers
#pragma unroll
    for (int mi = 0; mi < 4; mi++) {
#pragma unroll
        for (int reg = 0; reg < 4; reg++) {
            const int o = m0 + mi * 16 + q * 4 + reg;
            float s1 = 0.f, s2 = 0.f;
#pragma unroll
            for (int ni = 0; ni < 4; ni++) {
                const float v = acc[mi][ni][reg];
                out[((b * Oo + o) << 12) + hw0 + n0 + ni * 16 + r] = f2bf(v);
                s1 += v; s2 += v * v;
            }
#pragma unroll
            for (int d = 1; d < 16; d <<= 1) {
                s1 += __shfl_xor(s1, d);
                s2 += __shfl_xor(s2, d);
            }
            if (r == 0) {
                red[(hf * 2 + 0) * 128 + o] = s1;
                red[(hf * 2 + 1) * 128 + o] = s2;
            }
        }
    }
    __syncthreads();
    {
        const int o = t & 127;
        const int s = t >> 7;
        const float v = red[(0 + s) * 128 + o] + red[(2 + s) * 128 + o];
        const int blk = blockIdx.y * 32 + blockIdx.x;
        pstat[(size_t)(((((z << 7) | o) << 1) | s) << 9) | blk] = v;
    }
}

// ---------------- reduce partial stats -> per-channel coefficient float4 ----------------
// 128 blocks, one per channel o. coef[o] = (gs, xs, gh+xh, psi_w[o])
__global__ void finalize1(const float* __restrict__ pstat,
                          const float* __restrict__ wg_gamma, const float* __restrict__ wg_beta,
                          const float* __restrict__ wx_gamma, const float* __restrict__ wx_beta,
                          const float* __restrict__ psi_w, float4* __restrict__ coef)
{
    const int o = blockIdx.x;
    const int t = threadIdx.x;
    const float* r00 = pstat + (size_t)(((0 * 128 + o) * 2 + 0)) * 512;
    const float* r01 = pstat + (size_t)(((0 * 128 + o) * 2 + 1)) * 512;
    const float* r10 = pstat + (size_t)(((1 * 128 + o) * 2 + 0)) * 512;
    const float* r11 = pstat + (size_t)(((1 * 128 + o) * 2 + 1)) * 512;
    float s1g = r00[t] + r00[t + 256];
    float s2g = r01[t] + r01[t + 256];
    float s1x = r10[t] + r10[t + 256];
    float s2x = r11[t] + r11[t + 256];
#pragma unroll
    for (int d = 1; d < 64; d <<= 1) {
        s1g += __shfl_xor(s1g, d);
        s2g += __shfl_xor(s2g, d);
        s1x += __shfl_xor(s1x, d);
        s2x += __shfl_xor(s2x, d);
    }
    __shared__ float rr[4][4];
    const int wv = t >> 6, lid = t & 63;
    if (lid == 0) { rr[0][wv] = s1g; rr[1][wv] = s2g; rr[2][wv] = s1x; rr[3][wv] = s2x; }
    __syncthreads();
    if (t == 0) {
        const float invN = 1.f / (float)Ntot;
        const float S1g = rr[0][0] + rr[0][1] + rr[0][2] + rr[0][3];
        const float S2g = rr[1][0] + rr[1][1] + rr[1][2] + rr[1][3];
        const float S1x = rr[2][0] + rr[2][1] + rr[2][2] + rr[2][3];
        const float S2x = rr[3][0] + rr[3][1] + rr[3][2] + rr[3][3];
        const float mg = S1g * invN;
        const float vg = S2g * invN - mg * mg;
        const float gs = wg_gamma[o] * rsqrtf(vg + 1e-5f);
        const float gh = wg_beta[o] - mg * gs;
        const float mx = S1x * invN;
        const float vx = S2x * invN - mx * mx;
        const float xs = wx_gamma[o] * rsqrtf(vx + 1e-5f);
        const float xh = wx_beta[o] - mx * xs;
        coef[o] = make_float4(gs, xs, gh + xh, psi_w[o]);
    }
}

// ---------------- psi: S[p] = sum_o pw*relu(gs*tg + xs*tx + ch), + stat partials ----------
// 256 blocks x 256 threads, one thread per pixel. Coalesced 2B loads (64 lanes x consec hw).
__global__ __launch_bounds__(256)
void psi_k(const unsigned short* __restrict__ tg, const unsigned short* __restrict__ tx,
           const float4* __restrict__ coef, float* __restrict__ S, float* __restrict__ pp)
{
    __shared__ float4 cf[128];
    const int t = threadIdx.x;
    if (t < 128) cf[t] = coef[t];
    __syncthreads();

    const int p  = blockIdx.x * 256 + t;
    const int b  = p >> 12;
    const int hw = p & 4095;
    const unsigned short* gp = tg + (((size_t)(b * Oo)) << 12) + hw;
    const unsigned short* xp = tx + (((size_t)(b * Oo)) << 12) + hw;
    float s = 0.f;
#pragma unroll 16
    for (int o = 0; o < 128; o++) {
        const float gv = bf2f(gp[(size_t)o << 12]);
        const float xv = bf2f(xp[(size_t)o << 12]);
        const float4 c = cf[o];
        s += c.w * fmaxf(c.x * gv + c.y * xv + c.z, 0.f);
    }
    S[p] = s;   // psi bias cancels in BN2

    float s1 = s, s2 = s * s;
#pragma unroll
    for (int d = 1; d < 64; d <<= 1) {
        s1 += __shfl_xor(s1, d);
        s2 += __shfl_xor(s2, d);
    }
    __shared__ float r1[4], r2[4];
    const int wv = t >> 6, lid = t & 63;
    if (lid == 0) { r1[wv] = s1; r2[wv] = s2; }
    __syncthreads();
    if (t == 0) {
        pp[blockIdx.x]       = r1[0] + r1[1] + r1[2] + r1[3];
        pp[256 + blockIdx.x] = r2[0] + r2[1] + r2[2] + r2[3];
    }
}

// ---------------- reduce psi stat partials -> sigmoid scale/shift ----------------
__global__ void finalize2(const float* __restrict__ pp, const float* __restrict__ psi_gamma,
                          const float* __restrict__ psi_beta, float* __restrict__ pc)
{
    const int t = threadIdx.x;
    float s1 = pp[t];
    float s2 = pp[256 + t];
#pragma unroll
    for (int d = 1; d < 64; d <<= 1) {
        s1 += __shfl_xor(s1, d);
        s2 += __shfl_xor(s2, d);
    }
    __shared__ float a1[4], a2[4];
    const int wid = t >> 6, lid = t & 63;
    if (lid == 0) { a1[wid] = s1; a2[wid] = s2; }
    __syncthreads();
    if (t == 0) {
        const float invN = 1.f / (float)Ntot;
        const float S1 = a1[0] + a1[1] + a1[2] + a1[3];
        const float S2 = a2[0] + a2[1] + a2[2] + a2[3];
        const float m = S1 * invN;
        const float v = S2 * invN - m * m;
        const float ps = psi_gamma[0] * rsqrtf(v + 1e-5f);
        pc[0] = ps;
        pc[1] = psi_beta[0] - m * ps;
    }
}

// ---------------- out = x * sigmoid(pscale*s + pshift) ----------------
__global__ __launch_bounds__(256)
void final_mul_kernel(const float* __restrict__ x, const float* __restrict__ S,
                      const float* __restrict__ pc, float* __restrict__ out)
{
    const size_t i = ((size_t)blockIdx.x * 256 + threadIdx.x) * 4;
    const int hw = (int)(i & 4095);
    const size_t bc = i >> 12;
    const int b = (int)(bc >> 8);
    const float ps = pc[0], psh = pc[1];
    const float4 xv = *(const float4*)(x + i);
    const float4 sv = *(const float4*)(S + ((size_t)b << 12) + hw);
    float4 r;
    r.x = xv.x * (1.f / (1.f + __expf(-(ps * sv.x + psh))));
    r.y = xv.y * (1.f / (1.f + __expf(-(ps * sv.y + psh))));
    r.z = xv.z * (1.f / (1.f + __expf(-(ps * sv.z + psh))));
    r.w = xv.w * (1.f / (1.f + __expf(-(ps * sv.w + psh))));
    *(float4*)(out + i) = r;
}

extern "C" void kernel_launch(void* const* d_in, const int* in_sizes, int n_in,
                              void* d_out, int out_size, void* d_ws, size_t ws_size,
                              hipStream_t stream)
{
    const float* g         = (const float*)d_in[0];
    const float* x         = (const float*)d_in[1];
    const float* wg_w      = (const float*)d_in[2];
    const float* wg_gamma  = (const float*)d_in[4];
    const float* wg_beta   = (const float*)d_in[5];
    const float* wx_w      = (const float*)d_in[6];
    const float* wx_gamma  = (const float*)d_in[8];
    const float* wx_beta   = (const float*)d_in[9];
    const float* psi_w     = (const float*)d_in[10];
    const float* psi_gamma = (const float*)d_in[12];
    const float* psi_beta  = (const float*)d_in[13];
    // biases d_in[3], d_in[7], d_in[11] cancel exactly under training-mode BN

    float* out = (float*)d_out;
    // d_out doubles as scratch for the bf16 conv outputs (32 MB of its 64 MB),
    // fully overwritten by final_mul_kernel afterwards.
    unsigned short* tg = (unsigned short*)out;                         // 16 MB
    unsigned short* tx = (unsigned short*)out + (size_t)Bn * Oo * HWn; // next 16 MB

    float* ws    = (float*)d_ws;
    float* S     = ws;                          // 65536 floats
    float* pstat = ws + 65536;                  // 262144 floats: [(z,o,s) 512 rows][512 blocks]
    float4* coef = (float4*)(ws + 327680);      // 128 float4
    float* pp    = ws + 327680 + 512;           // 512 floats
    float* pc    = ws + 328704;                 // 2

    // no memsets: every buffer is fully written before being read

    conv_mfma<<<dim3(HWn / 128, Bn, 2), 256, 0, stream>>>(
        g, x, wg_w, wx_w, tg, tx, pstat);
    finalize1<<<128, 256, 0, stream>>>(pstat, wg_gamma, wg_beta, wx_gamma, wx_beta,
                                       psi_w, coef);
    psi_k<<<256, 256, 0, stream>>>(tg, tx, coef, S, pp);
    finalize2<<<1, 256, 0, stream>>>(pp, psi_gamma, psi_beta, pc);
    final_mul_kernel<<<(Ntot * Cc) / (4 * 256), 256, 0, stream>>>(x, S, pc, out);
}